// Round 7
// baseline (218.845 us; speedup 1.0000x reference)
//
#include <hip/hip_runtime.h>
#include <hip/hip_fp16.h>
#include <math.h>

// GAT layer: N=50000, E=800000, IN=256, H=4, C=32.
// R16: two levers.
// (1) k_gs GEMM blocks widened to 512 thr (8 waves, 256 rows): same 66KB
//     LDS -> 2 blocks/CU now gives 16 waves/CU (was 8); W staged once
//     per 256 rows (halves W traffic). Epilogue two-passes through cs
//     (stride 132, col-tile offset 33 -> conflict-free 4-head reads).
// (2) h stored as 4 PER-HEAD tables of N*32 bf16 (3.2MB each -- fits a
//     4MB per-XCD L2). k_agg splits per (head, node-chunk) with blockIdx
//     encoded so XCD x (round-robin bid%8, m09) always runs head x%4:
//     gather footprint per XCD = its own 3.2MB table -> L2-resident.
//     8 lanes/node, 4ch/lane ushort4, adj shfl-broadcast width 8.
// R14 fixed-capacity buckets, R13 fused bucket kernel retained.

#define NH 4
#define CH 32
#define HC 128
#define IND 256
#define NEG_SLOPE 0.2f
#define CSH 8           // coarse bucket = 256 nodes
#define NCB_MAX 256
#define CHUNK 4096
#define BCAP 6144       // records per coarse bucket (fixed capacity)

typedef __attribute__((ext_vector_type(8))) short bf16x8;
typedef __attribute__((ext_vector_type(16))) float f32x16;

__device__ __forceinline__ unsigned short f2bf(float f) {
    unsigned int u = __float_as_uint(f);
    unsigned int r = (u + 0x7FFFu + ((u >> 16) & 1u)) >> 16;   // RNE
    return (unsigned short)r;
}
__device__ __forceinline__ float bf2f(unsigned short s) {
    return __uint_as_float(((unsigned int)s) << 16);
}

// WT_bf[c][k] = bf16(W[k][c]) — one-time transpose+convert.
// Block 0 zeroes both bucket cursor arrays.
__global__ __launch_bounds__(256) void k_wprep(const float* __restrict__ W,
                                               unsigned short* __restrict__ WT_bf,
                                               int* __restrict__ gcurS,
                                               int* __restrict__ gcurD) {
    int t = blockIdx.x * 256 + threadIdx.x;
    if (blockIdx.x == 0) { gcurS[threadIdx.x] = 0; gcurD[threadIdx.x] = 0; }
    if (t < IND * HC) {
        int c = t >> 8;
        int k = t & 255;
        WT_bf[t] = f2bf(W[k * HC + c]);
    }
}

// Fused scatter + GEMM, 512 threads/block.
// Blocks [0,nsb): chunked LDS-binned scatter into fixed-capacity coarse
// streams (both sides). Blocks [nsb,nsb+ngb): MFMA GEMM over 256 rows
// (8 waves x 32 rows), writing per-head h tables + al/ar head-dots.
__global__ __launch_bounds__(512) void k_gs(const float* __restrict__ x,
                                            const unsigned short* __restrict__ WT_bf,
                                            const float* __restrict__ att,
                                            unsigned short* __restrict__ h_bf,
                                            float* __restrict__ al,
                                            float* __restrict__ ar,
                                            const int* __restrict__ ei,
                                            int* __restrict__ gcurS,
                                            int* __restrict__ gcurD,
                                            unsigned int* __restrict__ recS,
                                            unsigned int* __restrict__ recD,
                                            int E, int NE, int ncb, int nsb, int N) {
    __shared__ float cs[128 * 132];                    // 67584 B (both paths)

    const int tid = threadIdx.x;

    if (blockIdx.x < nsb) {
        // ================= scatter path (512 thr) =================
        unsigned int* srt = (unsigned int*)cs;                 // CHUNK u32 = 16KB
        int* cnt  = (int*)(srt + CHUNK);
        int* off  = cnt + NCB_MAX;
        int* cur  = off + NCB_MAX;
        int* gpos = cur + NCB_MAX;
        int* sc   = gpos + NCB_MAX;                            // +5KB

        const int t0 = blockIdx.x * CHUNK;
        const int m  = min(CHUNK, NE - t0);

        unsigned int myrec[CHUNK / 512];
        int nmy = 0;
        for (int i = tid; i < m; i += 512) {
            int t = t0 + i;
            int src, dst;
            if (t < E) { src = ei[t]; dst = ei[E + t]; }
            else       { src = dst = t - E; }
            myrec[nmy++] = (unsigned int)src | ((unsigned int)dst << 16);
        }

        for (int side = 0; side < 2; side++) {   // 0 = S (by src), 1 = D (by dst)
            if (tid < 256) cnt[tid] = 0;
            __syncthreads();
            int mybkt[CHUNK / 512];
            for (int k = 0; k < nmy; k++) {
                unsigned int r = myrec[k];
                int node = side ? (int)(r >> 16) : (int)(r & 0xFFFFu);
                mybkt[k] = node >> CSH;
                atomicAdd(&cnt[mybkt[k]], 1);
            }
            __syncthreads();
            int v = (tid < 256) ? cnt[tid] : 0;
            if (tid < 256) sc[tid] = v;
            __syncthreads();
            for (int o = 1; o < 256; o <<= 1) {
                int t = (tid >= o && tid < 256) ? sc[tid - o] : 0;
                __syncthreads();
                if (tid < 256) sc[tid] += t;
                __syncthreads();
            }
            if (tid < 256) { off[tid] = sc[tid] - v; cur[tid] = sc[tid] - v; }
            __syncthreads();
            for (int k = 0; k < nmy; k++) {
                int p = atomicAdd(&cur[mybkt[k]], 1);
                srt[p] = myrec[k];
            }
            __syncthreads();
            int* gcur = side ? gcurD : gcurS;
            if (tid < ncb) {
                int c = cnt[tid];
                gpos[tid] = c ? atomicAdd(&gcur[tid], c) : 0;
            }
            __syncthreads();
            unsigned int* recX = side ? recD : recS;
            for (int i = tid; i < m; i += 512) {
                unsigned int r = srt[i];
                int node = side ? (int)(r >> 16) : (int)(r & 0xFFFFu);
                int cb = node >> CSH;
                int p  = gpos[cb] + (i - off[cb]);
                if (p < BCAP)                     // 27-sigma safety clamp
                    recX[(size_t)cb * BCAP + p] = r;
            }
            __syncthreads();
        }
        return;
    }

    // ================= GEMM path (512 thr, 256 rows) =================
    unsigned short* wsT = (unsigned short*)cs;         // [128][258] = 66048 B

    const int row0 = (blockIdx.x - nsb) * 256;
    const int wave = tid >> 6;                         // 0..7
    const int lane = tid & 63;
    const int n32  = lane & 31;
    const int half = lane >> 5;

    // stage full W once: thread copies quarter column (64 shorts, int4 x8)
    {
        int c  = tid >> 2;
        int kq = (tid & 3) * 64;
        const unsigned short* src = WT_bf + c * IND + kq;
        unsigned short* dst = wsT + c * 258 + kq;
#pragma unroll
        for (int j = 0; j < 64; j += 8)
            *(int4*)(dst + j) = *(const int4*)(src + j);
    }
    __syncthreads();

    const int row   = row0 + wave * 32 + n32;
    const bool valid = row < N;
    const float* xrow = x + (size_t)row * IND + half * 8;

    f32x16 acc[4];
#pragma unroll
    for (int t = 0; t < 4; t++)
#pragma unroll
        for (int r = 0; r < 16; r++) acc[t][r] = 0.0f;

    // 16 K-steps of 16; NO barriers inside.
#pragma unroll 4
    for (int s = 0; s < 16; s++) {
        float4 v0 = make_float4(0.f, 0.f, 0.f, 0.f);
        float4 v1 = v0;
        if (valid) {
            v0 = *(const float4*)(xrow + s * 16);
            v1 = *(const float4*)(xrow + s * 16 + 4);
        }
        bf16x8 a;
        a[0] = (short)f2bf(v0.x); a[1] = (short)f2bf(v0.y);
        a[2] = (short)f2bf(v0.z); a[3] = (short)f2bf(v0.w);
        a[4] = (short)f2bf(v1.x); a[5] = (short)f2bf(v1.y);
        a[6] = (short)f2bf(v1.z); a[7] = (short)f2bf(v1.w);
#pragma unroll
        for (int t = 0; t < 4; t++) {
            bf16x8 b = *(const bf16x8*)(wsT + (t * 32 + n32) * 258 + s * 16 + half * 8);
            acc[t] = __builtin_amdgcn_mfma_f32_32x32x16_bf16(a, b, acc[t], 0, 0, 0);
        }
    }
    __syncthreads();   // wsT dead; cs aliases it

    // Two passes: waves 0-3 then 4-7 stage their C tiles through cs.
    // cs stride 132, col-tile t at offset 33t: epilogue reads
    // addr = rl*132 + hq*33 + c -> bank (4rl+hq+c)%32, conflict-free.
    const size_t NT = (size_t)N * 32;                  // per-head table stride
    for (int pass = 0; pass < 2; pass++) {
        if ((wave >> 2) == pass) {
            const int lw = wave & 3;
#pragma unroll
            for (int t = 0; t < 4; t++)
#pragma unroll
                for (int r = 0; r < 16; r++) {
                    int rl = lw * 32 + (r & 3) + 8 * (r >> 2) + 4 * half;
                    cs[rl * 132 + t * 33 + n32] = acc[t][r];
                }
        }
        __syncthreads();

        // epilogue: 4 threads/row, thread = (rl = tid>>2, head hq = tid&3)
        const int rl   = tid >> 2;
        const int hq   = tid & 3;
        const int orow = row0 + pass * 128 + rl;
        if (orow < N) {
            const float* cr = cs + rl * 132 + hq * 33;
            unsigned short* hp = h_bf + (size_t)hq * NT + (size_t)orow * 32;
#pragma unroll
            for (int c = 0; c < 32; c += 8) {
                ushort4 o0, o1;
                o0.x = f2bf(cr[c]);     o0.y = f2bf(cr[c + 1]);
                o0.z = f2bf(cr[c + 2]); o0.w = f2bf(cr[c + 3]);
                o1.x = f2bf(cr[c + 4]); o1.y = f2bf(cr[c + 5]);
                o1.z = f2bf(cr[c + 6]); o1.w = f2bf(cr[c + 7]);
                *(ushort4*)(hp + c) = o0;
                *(ushort4*)(hp + c + 4) = o1;
            }
            const float* w0 = att + hq * (2 * CH);
            float sl = 0.f, sr = 0.f;
#pragma unroll
            for (int c = 0; c < CH; c++) {
                float v = cr[c];
                sl += v * w0[c];
                sr += v * w0[CH + c];
            }
            al[orow * NH + hq] = sl;
            ar[orow * NH + hq] = sr;
        }
        __syncthreads();   // before pass B overwrites cs
    }
}

// Fused bucket kernel, 2*ncb blocks:
//   blocks [0,ncb):     D-side rebin -> node-level CSR (adjD + rowB/rowE)
//   blocks [ncb,2*ncb): S-side LDS-binned denominator -> arw={ar,1/sum}
// S-side loop 2x unrolled (two al-gathers in flight per thread).
__global__ __launch_bounds__(256) void k_bucket(const unsigned int* __restrict__ recS,
                                                const unsigned int* __restrict__ recD,
                                                const int* __restrict__ gcurS,
                                                const int* __restrict__ gcurD,
                                                const float* __restrict__ al,
                                                const float* __restrict__ ar,
                                                unsigned short* __restrict__ adjD,
                                                int* __restrict__ rowB,
                                                int* __restrict__ rowE,
                                                float* __restrict__ arw,
                                                int ncb, int N) {
    __shared__ int cnt[256], cur[256], sc[256];   // 3 KB (rebin side)
    __shared__ float lsums[256 * NH];             // 4 KB (denom side)
    __shared__ float lar[256 * NH];               // 4 KB (denom side)
    const int tid = threadIdx.x;

    if (blockIdx.x < ncb) {
        // ---- D-side rebin ----
        const int cb = blockIdx.x;
        const int b0 = cb * BCAP;
        const int tot_rec = min(gcurD[cb], BCAP);

        cnt[tid] = 0;
        __syncthreads();
        for (int i = tid; i < tot_rec; i += 256) {
            unsigned int r = recD[b0 + i];
            atomicAdd(&cnt[(r >> 16) & 255], 1);
        }
        __syncthreads();
        int v = cnt[tid];
        sc[tid] = v;
        __syncthreads();
        for (int o = 1; o < 256; o <<= 1) {
            int t = (tid >= o) ? sc[tid - o] : 0;
            __syncthreads();
            sc[tid] += t;
            __syncthreads();
        }
        int ex = sc[tid] - v;
        int node_g = (cb << CSH) + tid;
        if (node_g < N) { rowB[node_g] = b0 + ex; rowE[node_g] = b0 + ex + v; }
        cur[tid] = ex;
        __syncthreads();
        for (int i = tid; i < tot_rec; i += 256) {
            unsigned int r = recD[b0 + i];
            int node = (int)(r >> 16) & 255;
            int p = atomicAdd(&cur[node], 1);
            adjD[b0 + p] = (unsigned short)(r & 0xFFFFu);
        }
    } else {
        // ---- S-side denominator + arw pack ----
        const int cb = blockIdx.x - ncb;
        const int b0 = cb * BCAP;
        const int b1 = b0 + min(gcurS[cb], BCAP);
        const int node_g = (cb << CSH) + tid;

        float4 arv = make_float4(0.f, 0.f, 0.f, 0.f);
        if (node_g < N) arv = *(const float4*)(ar + (size_t)node_g * NH);
        *(float4*)(lar + tid * NH) = arv;
        *(float4*)(lsums + tid * NH) = make_float4(0.f, 0.f, 0.f, 0.f);
        __syncthreads();

        int i = b0 + tid;
        for (; i + 256 < b1; i += 512) {
            unsigned int r0 = recS[i];
            unsigned int r1 = recS[i + 256];
            int sl0 = (int)(r0 & 255u), dst0 = (int)(r0 >> 16);
            int sl1 = (int)(r1 & 255u), dst1 = (int)(r1 >> 16);
            float4 av0 = *(const float4*)(al + (size_t)dst0 * NH);
            float4 av1 = *(const float4*)(al + (size_t)dst1 * NH);
            const float* w0 = lar + sl0 * NH;
            const float* w1 = lar + sl1 * NH;
            float a0 = av0.x + w0[0], a1 = av0.y + w0[1];
            float a2 = av0.z + w0[2], a3 = av0.w + w0[3];
            float c0 = av1.x + w1[0], c1 = av1.y + w1[1];
            float c2 = av1.z + w1[2], c3 = av1.w + w1[3];
            a0 = (a0 > 0.f) ? a0 : NEG_SLOPE * a0;
            a1 = (a1 > 0.f) ? a1 : NEG_SLOPE * a1;
            a2 = (a2 > 0.f) ? a2 : NEG_SLOPE * a2;
            a3 = (a3 > 0.f) ? a3 : NEG_SLOPE * a3;
            c0 = (c0 > 0.f) ? c0 : NEG_SLOPE * c0;
            c1 = (c1 > 0.f) ? c1 : NEG_SLOPE * c1;
            c2 = (c2 > 0.f) ? c2 : NEG_SLOPE * c2;
            c3 = (c3 > 0.f) ? c3 : NEG_SLOPE * c3;
            float* s0 = lsums + sl0 * NH;
            float* s1 = lsums + sl1 * NH;
            atomicAdd(s0 + 0, __expf(a0));
            atomicAdd(s0 + 1, __expf(a1));
            atomicAdd(s0 + 2, __expf(a2));
            atomicAdd(s0 + 3, __expf(a3));
            atomicAdd(s1 + 0, __expf(c0));
            atomicAdd(s1 + 1, __expf(c1));
            atomicAdd(s1 + 2, __expf(c2));
            atomicAdd(s1 + 3, __expf(c3));
        }
        if (i < b1) {
            unsigned int r = recS[i];
            int slot = (int)(r & 255u);
            int dst  = (int)(r >> 16);
            float4 alv = *(const float4*)(al + (size_t)dst * NH);
            const float* av = lar + slot * NH;
            float a0 = alv.x + av[0], a1 = alv.y + av[1];
            float a2 = alv.z + av[2], a3 = alv.w + av[3];
            a0 = (a0 > 0.f) ? a0 : NEG_SLOPE * a0;
            a1 = (a1 > 0.f) ? a1 : NEG_SLOPE * a1;
            a2 = (a2 > 0.f) ? a2 : NEG_SLOPE * a2;
            a3 = (a3 > 0.f) ? a3 : NEG_SLOPE * a3;
            float* sp = lsums + slot * NH;
            atomicAdd(sp + 0, __expf(a0));
            atomicAdd(sp + 1, __expf(a1));
            atomicAdd(sp + 2, __expf(a2));
            atomicAdd(sp + 3, __expf(a3));
        }
        __syncthreads();

        if (node_g < N) {
            const float* sp = lsums + tid * NH;
            float4 p0 = make_float4(arv.x, 1.0f / (sp[0] + 1e-16f),
                                    arv.y, 1.0f / (sp[1] + 1e-16f));
            float4 p1 = make_float4(arv.z, 1.0f / (sp[2] + 1e-16f),
                                    arv.w, 1.0f / (sp[3] + 1e-16f));
            *(float4*)(arw + (size_t)node_g * 8)     = p0;
            *(float4*)(arw + (size_t)node_g * 8 + 4) = p1;
        }
    }
}

// Head-split fused weight+aggregate, XCD-pinned.
// bid%8 = XCD (round-robin dispatch, m09): head h = bid&3, node-parity
// p = (bid>>2)&1, chunk = (bid>>3)*2+p -> XCD x always runs head x%4,
// so each XCD's gather footprint = one 3.2MB per-head table (L2-fit).
// 32 nodes/block, 8 lanes/node, 4ch/lane (ushort4 = 8B gathers); adj
// preloaded 8-at-a-time and shfl-broadcast (width 8); weight from one
// 8B arw load per edge; 2-edge unroll.
__global__ __launch_bounds__(256) void k_agg(const int* __restrict__ rowB,
                                             const int* __restrict__ rowE,
                                             const unsigned short* __restrict__ adjD,
                                             const float* __restrict__ al,
                                             const float* __restrict__ arw,
                                             const unsigned short* __restrict__ h_bf,
                                             const float* __restrict__ bias,
                                             float* __restrict__ out, int N) {
    const int h     = blockIdx.x & 3;
    const int p     = (blockIdx.x >> 2) & 1;
    const int chunk = (blockIdx.x >> 3) * 2 + p;
    const int n     = chunk * 32 + (threadIdx.x >> 3);
    if (n >= N) return;
    const int sl = threadIdx.x & 7;
    const unsigned short* htab = h_bf + (size_t)h * N * 32;
    const int beg = rowB[n], end = rowE[n];
    const float alh = al[n * NH + h];

    float a0 = 0.f, a1 = 0.f, a2 = 0.f, a3 = 0.f;

    for (int base = beg; base < end; base += 8) {
        int idx = base + sl;
        int av  = (idx < end) ? (int)adjD[idx] : 0;   // coop preload
        int cnt = min(8, end - base);
        int e = 0;
        for (; e + 2 <= cnt; e += 2) {
            int s0 = __shfl(av, e,     8);
            int s1 = __shfl(av, e + 1, 8);
            ushort4 u0 = *(const ushort4*)(htab + (size_t)s0 * 32 + sl * 4);
            ushort4 u1 = *(const ushort4*)(htab + (size_t)s1 * 32 + sl * 4);
            float2 p0 = *(const float2*)(arw + (size_t)s0 * 8 + h * 2);
            float2 p1 = *(const float2*)(arw + (size_t)s1 * 8 + h * 2);
            float t0 = alh + p0.x; t0 = (t0 > 0.f) ? t0 : NEG_SLOPE * t0;
            float t1 = alh + p1.x; t1 = (t1 > 0.f) ? t1 : NEG_SLOPE * t1;
            float w0 = __expf(t0) * p0.y;
            float w1 = __expf(t1) * p1.y;
            a0 += bf2f(u0.x) * w0 + bf2f(u1.x) * w1;
            a1 += bf2f(u0.y) * w0 + bf2f(u1.y) * w1;
            a2 += bf2f(u0.z) * w0 + bf2f(u1.z) * w1;
            a3 += bf2f(u0.w) * w0 + bf2f(u1.w) * w1;
        }
        if (e < cnt) {
            int s0 = __shfl(av, e, 8);
            ushort4 u0 = *(const ushort4*)(htab + (size_t)s0 * 32 + sl * 4);
            float2 p0 = *(const float2*)(arw + (size_t)s0 * 8 + h * 2);
            float t0 = alh + p0.x; t0 = (t0 > 0.f) ? t0 : NEG_SLOPE * t0;
            float w0 = __expf(t0) * p0.y;
            a0 += bf2f(u0.x) * w0;
            a1 += bf2f(u0.y) * w0;
            a2 += bf2f(u0.z) * w0;
            a3 += bf2f(u0.w) * w0;
        }
    }
    const int c0 = h * CH + sl * 4;
    float4 b4 = *(const float4*)(bias + c0);
    *(float4*)(out + (size_t)n * HC + c0) =
        make_float4(a0 + b4.x, a1 + b4.y, a2 + b4.z, a3 + b4.w);
}

extern "C" void kernel_launch(void* const* d_in, const int* in_sizes, int n_in,
                              void* d_out, int out_size, void* d_ws, size_t ws_size,
                              hipStream_t stream) {
    const float* x    = (const float*)d_in[0];
    const float* W    = (const float*)d_in[1];
    const float* att  = (const float*)d_in[2];
    const float* bias = (const float*)d_in[3];
    const int*   ei   = (const int*)d_in[4];

    const int N  = in_sizes[0] / IND;     // 50000
    const int E  = in_sizes[4] / 2;       // 800000
    const int NE = E + N;
    const int ncb = (N + (1 << CSH) - 1) >> CSH;   // 196
    const int nsb = (NE + CHUNK - 1) / CHUNK;      // 208 scatter blocks
    const int ngb = (N + 255) / 256;               // 196 gemm blocks (512 thr)
    const int nch = (N + 31) / 32;                 // agg node chunks (1563)
    const int nab = ((nch + 1) / 2) * 8;           // agg blocks (6256)
    float* out = (float*)d_out;
    const int nodeTot = N * NH;
    const size_t capTot = (size_t)ncb * BCAP;      // 196*6144 ≈ 1.2M recs/side

    // ws layout
    unsigned short* h_bf  = (unsigned short*)d_ws;             // 4 tables N*32 u16
    unsigned short* WT_bf = h_bf + (size_t)N * HC;             // 32K u16
    float* al   = (float*)(WT_bf + IND * HC);                  // N*4 f32
    float* ar   = al + nodeTot;                                // N*4
    float* arw  = ar + nodeTot;                                // N*8 = 1.6MB
    unsigned int* recS = (unsigned int*)(arw + (size_t)N * 8); // ncb*BCAP u32
    unsigned int* recD = recS + capTot;                        // ncb*BCAP u32
    unsigned short* adjD = (unsigned short*)(recD + capTot);   // ncb*BCAP u16
    int* rowB    = (int*)(adjD + capTot + (capTot & 1));       // N
    int* rowE    = rowB + N;                                   // N
    int* gcurS   = rowE + N;                                   // ncb
    int* gcurD   = gcurS + NCB_MAX;                            // ncb

    k_wprep<<<(IND * HC + 255) / 256, 256, 0, stream>>>(W, WT_bf, gcurS, gcurD);
    k_gs<<<nsb + ngb, 512, 0, stream>>>(x, WT_bf, att, h_bf, al, ar, ei,
                                        gcurS, gcurD, recS, recD,
                                        E, NE, ncb, nsb, N);
    k_bucket<<<2 * ncb, 256, 0, stream>>>(recS, recD, gcurS, gcurD, al, ar,
                                          adjD, rowB, rowE, arw, ncb, N);
    k_agg<<<nab, 256, 0, stream>>>(rowB, rowE, adjD, al, arw, h_bf,
                                   bias, out, N);
}

// Round 8
// 204.896 us; speedup vs baseline: 1.0681x; 1.0681x over previous
//
#include <hip/hip_runtime.h>
#include <hip/hip_fp16.h>
#include <math.h>

// GAT layer: N=50000, E=800000, IN=256, H=4, C=32.
// R17: revert R16's head-split agg (4x per-edge overhead, XCD pinning
// unproven -> 55us vs 41.7 floor). h back to interleaved [n][128];
// k_agg back to R14 form (8 nodes/block, 32 lanes/node, ushort4 8B
// gathers, shfl-32 adj broadcast, 4-edge unroll). KEEP R16's 512-thread
// GEMM (8 waves, 256 rows, 16 waves/CU at 66KB LDS, W staged once per
// 256 rows) with two-pass epilogue writing interleaved h + al/ar.
// R14 fixed-capacity buckets, R13 fused bucket kernel retained.

#define NH 4
#define CH 32
#define HC 128
#define IND 256
#define NEG_SLOPE 0.2f
#define CSH 8           // coarse bucket = 256 nodes
#define NCB_MAX 256
#define CHUNK 4096
#define BCAP 6144       // records per coarse bucket (fixed capacity)

typedef __attribute__((ext_vector_type(8))) short bf16x8;
typedef __attribute__((ext_vector_type(16))) float f32x16;

__device__ __forceinline__ unsigned short f2bf(float f) {
    unsigned int u = __float_as_uint(f);
    unsigned int r = (u + 0x7FFFu + ((u >> 16) & 1u)) >> 16;   // RNE
    return (unsigned short)r;
}
__device__ __forceinline__ float bf2f(unsigned short s) {
    return __uint_as_float(((unsigned int)s) << 16);
}

// WT_bf[c][k] = bf16(W[k][c]) — one-time transpose+convert.
// Block 0 zeroes both bucket cursor arrays.
__global__ __launch_bounds__(256) void k_wprep(const float* __restrict__ W,
                                               unsigned short* __restrict__ WT_bf,
                                               int* __restrict__ gcurS,
                                               int* __restrict__ gcurD) {
    int t = blockIdx.x * 256 + threadIdx.x;
    if (blockIdx.x == 0) { gcurS[threadIdx.x] = 0; gcurD[threadIdx.x] = 0; }
    if (t < IND * HC) {
        int c = t >> 8;
        int k = t & 255;
        WT_bf[t] = f2bf(W[k * HC + c]);
    }
}

// Fused scatter + GEMM, 512 threads/block.
// Blocks [0,nsb): chunked LDS-binned scatter into fixed-capacity coarse
// streams (both sides). Blocks [nsb,nsb+ngb): MFMA GEMM over 256 rows
// (8 waves x 32 rows), writing interleaved h_bf[n][128] + al/ar dots.
__global__ __launch_bounds__(512) void k_gs(const float* __restrict__ x,
                                            const unsigned short* __restrict__ WT_bf,
                                            const float* __restrict__ att,
                                            unsigned short* __restrict__ h_bf,
                                            float* __restrict__ al,
                                            float* __restrict__ ar,
                                            const int* __restrict__ ei,
                                            int* __restrict__ gcurS,
                                            int* __restrict__ gcurD,
                                            unsigned int* __restrict__ recS,
                                            unsigned int* __restrict__ recD,
                                            int E, int NE, int ncb, int nsb, int N) {
    __shared__ float cs[128 * 132];                    // 67584 B (both paths)

    const int tid = threadIdx.x;

    if (blockIdx.x < nsb) {
        // ================= scatter path (512 thr) =================
        unsigned int* srt = (unsigned int*)cs;                 // CHUNK u32 = 16KB
        int* cnt  = (int*)(srt + CHUNK);
        int* off  = cnt + NCB_MAX;
        int* cur  = off + NCB_MAX;
        int* gpos = cur + NCB_MAX;
        int* sc   = gpos + NCB_MAX;                            // +5KB

        const int t0 = blockIdx.x * CHUNK;
        const int m  = min(CHUNK, NE - t0);

        unsigned int myrec[CHUNK / 512];
        int nmy = 0;
        for (int i = tid; i < m; i += 512) {
            int t = t0 + i;
            int src, dst;
            if (t < E) { src = ei[t]; dst = ei[E + t]; }
            else       { src = dst = t - E; }
            myrec[nmy++] = (unsigned int)src | ((unsigned int)dst << 16);
        }

        for (int side = 0; side < 2; side++) {   // 0 = S (by src), 1 = D (by dst)
            if (tid < 256) cnt[tid] = 0;
            __syncthreads();
            int mybkt[CHUNK / 512];
            for (int k = 0; k < nmy; k++) {
                unsigned int r = myrec[k];
                int node = side ? (int)(r >> 16) : (int)(r & 0xFFFFu);
                mybkt[k] = node >> CSH;
                atomicAdd(&cnt[mybkt[k]], 1);
            }
            __syncthreads();
            int v = (tid < 256) ? cnt[tid] : 0;
            if (tid < 256) sc[tid] = v;
            __syncthreads();
            for (int o = 1; o < 256; o <<= 1) {
                int t = (tid >= o && tid < 256) ? sc[tid - o] : 0;
                __syncthreads();
                if (tid < 256) sc[tid] += t;
                __syncthreads();
            }
            if (tid < 256) { off[tid] = sc[tid] - v; cur[tid] = sc[tid] - v; }
            __syncthreads();
            for (int k = 0; k < nmy; k++) {
                int p = atomicAdd(&cur[mybkt[k]], 1);
                srt[p] = myrec[k];
            }
            __syncthreads();
            int* gcur = side ? gcurD : gcurS;
            if (tid < ncb) {
                int c = cnt[tid];
                gpos[tid] = c ? atomicAdd(&gcur[tid], c) : 0;
            }
            __syncthreads();
            unsigned int* recX = side ? recD : recS;
            for (int i = tid; i < m; i += 512) {
                unsigned int r = srt[i];
                int node = side ? (int)(r >> 16) : (int)(r & 0xFFFFu);
                int cb = node >> CSH;
                int p  = gpos[cb] + (i - off[cb]);
                if (p < BCAP)                     // 27-sigma safety clamp
                    recX[(size_t)cb * BCAP + p] = r;
            }
            __syncthreads();
        }
        return;
    }

    // ================= GEMM path (512 thr, 256 rows) =================
    unsigned short* wsT = (unsigned short*)cs;         // [128][258] = 66048 B

    const int row0 = (blockIdx.x - nsb) * 256;
    const int wave = tid >> 6;                         // 0..7
    const int lane = tid & 63;
    const int n32  = lane & 31;
    const int half = lane >> 5;

    // stage full W once: thread copies quarter column (64 shorts, int4 x8)
    {
        int c  = tid >> 2;
        int kq = (tid & 3) * 64;
        const unsigned short* src = WT_bf + c * IND + kq;
        unsigned short* dst = wsT + c * 258 + kq;
#pragma unroll
        for (int j = 0; j < 64; j += 8)
            *(int4*)(dst + j) = *(const int4*)(src + j);
    }
    __syncthreads();

    const int row   = row0 + wave * 32 + n32;
    const bool valid = row < N;
    const float* xrow = x + (size_t)row * IND + half * 8;

    f32x16 acc[4];
#pragma unroll
    for (int t = 0; t < 4; t++)
#pragma unroll
        for (int r = 0; r < 16; r++) acc[t][r] = 0.0f;

    // 16 K-steps of 16; NO barriers inside.
#pragma unroll 4
    for (int s = 0; s < 16; s++) {
        float4 v0 = make_float4(0.f, 0.f, 0.f, 0.f);
        float4 v1 = v0;
        if (valid) {
            v0 = *(const float4*)(xrow + s * 16);
            v1 = *(const float4*)(xrow + s * 16 + 4);
        }
        bf16x8 a;
        a[0] = (short)f2bf(v0.x); a[1] = (short)f2bf(v0.y);
        a[2] = (short)f2bf(v0.z); a[3] = (short)f2bf(v0.w);
        a[4] = (short)f2bf(v1.x); a[5] = (short)f2bf(v1.y);
        a[6] = (short)f2bf(v1.z); a[7] = (short)f2bf(v1.w);
#pragma unroll
        for (int t = 0; t < 4; t++) {
            bf16x8 b = *(const bf16x8*)(wsT + (t * 32 + n32) * 258 + s * 16 + half * 8);
            acc[t] = __builtin_amdgcn_mfma_f32_32x32x16_bf16(a, b, acc[t], 0, 0, 0);
        }
    }
    __syncthreads();   // wsT dead; cs aliases it

    // Two passes: waves 0-3 then 4-7 stage their C tiles through cs.
    // cs stride 132, col-tile t at offset 33t: epilogue reads
    // addr = rl*132 + hq*33 + c -> bank (4rl+hq+c)%32, conflict-free.
    for (int pass = 0; pass < 2; pass++) {
        if ((wave >> 2) == pass) {
            const int lw = wave & 3;
#pragma unroll
            for (int t = 0; t < 4; t++)
#pragma unroll
                for (int r = 0; r < 16; r++) {
                    int rl = lw * 32 + (r & 3) + 8 * (r >> 2) + 4 * half;
                    cs[rl * 132 + t * 33 + n32] = acc[t][r];
                }
        }
        __syncthreads();

        // epilogue: 4 threads/row, thread = (rl = tid>>2, head hq = tid&3)
        const int rl   = tid >> 2;
        const int hq   = tid & 3;
        const int orow = row0 + pass * 128 + rl;
        if (orow < N) {
            const float* cr = cs + rl * 132 + hq * 33;
            unsigned short* hp = h_bf + (size_t)orow * HC + hq * CH;
#pragma unroll
            for (int c = 0; c < 32; c += 8) {
                ushort4 o0, o1;
                o0.x = f2bf(cr[c]);     o0.y = f2bf(cr[c + 1]);
                o0.z = f2bf(cr[c + 2]); o0.w = f2bf(cr[c + 3]);
                o1.x = f2bf(cr[c + 4]); o1.y = f2bf(cr[c + 5]);
                o1.z = f2bf(cr[c + 6]); o1.w = f2bf(cr[c + 7]);
                *(ushort4*)(hp + c) = o0;
                *(ushort4*)(hp + c + 4) = o1;
            }
            const float* w0 = att + hq * (2 * CH);
            float sl = 0.f, sr = 0.f;
#pragma unroll
            for (int c = 0; c < CH; c++) {
                float v = cr[c];
                sl += v * w0[c];
                sr += v * w0[CH + c];
            }
            al[orow * NH + hq] = sl;
            ar[orow * NH + hq] = sr;
        }
        __syncthreads();   // before pass B overwrites cs
    }
}

// Fused bucket kernel, 2*ncb blocks:
//   blocks [0,ncb):     D-side rebin -> node-level CSR (adjD + rowB/rowE)
//   blocks [ncb,2*ncb): S-side LDS-binned denominator -> arw={ar,1/sum}
// S-side loop 2x unrolled (two al-gathers in flight per thread).
__global__ __launch_bounds__(256) void k_bucket(const unsigned int* __restrict__ recS,
                                                const unsigned int* __restrict__ recD,
                                                const int* __restrict__ gcurS,
                                                const int* __restrict__ gcurD,
                                                const float* __restrict__ al,
                                                const float* __restrict__ ar,
                                                unsigned short* __restrict__ adjD,
                                                int* __restrict__ rowB,
                                                int* __restrict__ rowE,
                                                float* __restrict__ arw,
                                                int ncb, int N) {
    __shared__ int cnt[256], cur[256], sc[256];   // 3 KB (rebin side)
    __shared__ float lsums[256 * NH];             // 4 KB (denom side)
    __shared__ float lar[256 * NH];               // 4 KB (denom side)
    const int tid = threadIdx.x;

    if (blockIdx.x < ncb) {
        // ---- D-side rebin ----
        const int cb = blockIdx.x;
        const int b0 = cb * BCAP;
        const int tot_rec = min(gcurD[cb], BCAP);

        cnt[tid] = 0;
        __syncthreads();
        for (int i = tid; i < tot_rec; i += 256) {
            unsigned int r = recD[b0 + i];
            atomicAdd(&cnt[(r >> 16) & 255], 1);
        }
        __syncthreads();
        int v = cnt[tid];
        sc[tid] = v;
        __syncthreads();
        for (int o = 1; o < 256; o <<= 1) {
            int t = (tid >= o) ? sc[tid - o] : 0;
            __syncthreads();
            sc[tid] += t;
            __syncthreads();
        }
        int ex = sc[tid] - v;
        int node_g = (cb << CSH) + tid;
        if (node_g < N) { rowB[node_g] = b0 + ex; rowE[node_g] = b0 + ex + v; }
        cur[tid] = ex;
        __syncthreads();
        for (int i = tid; i < tot_rec; i += 256) {
            unsigned int r = recD[b0 + i];
            int node = (int)(r >> 16) & 255;
            int p = atomicAdd(&cur[node], 1);
            adjD[b0 + p] = (unsigned short)(r & 0xFFFFu);
        }
    } else {
        // ---- S-side denominator + arw pack ----
        const int cb = blockIdx.x - ncb;
        const int b0 = cb * BCAP;
        const int b1 = b0 + min(gcurS[cb], BCAP);
        const int node_g = (cb << CSH) + tid;

        float4 arv = make_float4(0.f, 0.f, 0.f, 0.f);
        if (node_g < N) arv = *(const float4*)(ar + (size_t)node_g * NH);
        *(float4*)(lar + tid * NH) = arv;
        *(float4*)(lsums + tid * NH) = make_float4(0.f, 0.f, 0.f, 0.f);
        __syncthreads();

        int i = b0 + tid;
        for (; i + 256 < b1; i += 512) {
            unsigned int r0 = recS[i];
            unsigned int r1 = recS[i + 256];
            int sl0 = (int)(r0 & 255u), dst0 = (int)(r0 >> 16);
            int sl1 = (int)(r1 & 255u), dst1 = (int)(r1 >> 16);
            float4 av0 = *(const float4*)(al + (size_t)dst0 * NH);
            float4 av1 = *(const float4*)(al + (size_t)dst1 * NH);
            const float* w0 = lar + sl0 * NH;
            const float* w1 = lar + sl1 * NH;
            float a0 = av0.x + w0[0], a1 = av0.y + w0[1];
            float a2 = av0.z + w0[2], a3 = av0.w + w0[3];
            float c0 = av1.x + w1[0], c1 = av1.y + w1[1];
            float c2 = av1.z + w1[2], c3 = av1.w + w1[3];
            a0 = (a0 > 0.f) ? a0 : NEG_SLOPE * a0;
            a1 = (a1 > 0.f) ? a1 : NEG_SLOPE * a1;
            a2 = (a2 > 0.f) ? a2 : NEG_SLOPE * a2;
            a3 = (a3 > 0.f) ? a3 : NEG_SLOPE * a3;
            c0 = (c0 > 0.f) ? c0 : NEG_SLOPE * c0;
            c1 = (c1 > 0.f) ? c1 : NEG_SLOPE * c1;
            c2 = (c2 > 0.f) ? c2 : NEG_SLOPE * c2;
            c3 = (c3 > 0.f) ? c3 : NEG_SLOPE * c3;
            float* s0 = lsums + sl0 * NH;
            float* s1 = lsums + sl1 * NH;
            atomicAdd(s0 + 0, __expf(a0));
            atomicAdd(s0 + 1, __expf(a1));
            atomicAdd(s0 + 2, __expf(a2));
            atomicAdd(s0 + 3, __expf(a3));
            atomicAdd(s1 + 0, __expf(c0));
            atomicAdd(s1 + 1, __expf(c1));
            atomicAdd(s1 + 2, __expf(c2));
            atomicAdd(s1 + 3, __expf(c3));
        }
        if (i < b1) {
            unsigned int r = recS[i];
            int slot = (int)(r & 255u);
            int dst  = (int)(r >> 16);
            float4 alv = *(const float4*)(al + (size_t)dst * NH);
            const float* av = lar + slot * NH;
            float a0 = alv.x + av[0], a1 = alv.y + av[1];
            float a2 = alv.z + av[2], a3 = alv.w + av[3];
            a0 = (a0 > 0.f) ? a0 : NEG_SLOPE * a0;
            a1 = (a1 > 0.f) ? a1 : NEG_SLOPE * a1;
            a2 = (a2 > 0.f) ? a2 : NEG_SLOPE * a2;
            a3 = (a3 > 0.f) ? a3 : NEG_SLOPE * a3;
            float* sp = lsums + slot * NH;
            atomicAdd(sp + 0, __expf(a0));
            atomicAdd(sp + 1, __expf(a1));
            atomicAdd(sp + 2, __expf(a2));
            atomicAdd(sp + 3, __expf(a3));
        }
        __syncthreads();

        if (node_g < N) {
            const float* sp = lsums + tid * NH;
            float4 p0 = make_float4(arv.x, 1.0f / (sp[0] + 1e-16f),
                                    arv.y, 1.0f / (sp[1] + 1e-16f));
            float4 p1 = make_float4(arv.z, 1.0f / (sp[2] + 1e-16f),
                                    arv.w, 1.0f / (sp[3] + 1e-16f));
            *(float4*)(arw + (size_t)node_g * 8)     = p0;
            *(float4*)(arw + (size_t)node_g * 8 + 4) = p1;
        }
    }
}

// Fused weight+aggregate (R14 form — measured 41.7us floor).
// 8 nodes/block, 32 lanes/node, 4 channels/lane (ushort4 = 8B gathers).
// adj preloaded 32-at-a-time (one coalesced 2B load) and broadcast via
// __shfl -> no adj-load in the dependent chain. Weight from one packed
// 8B arw load per edge (L2-hot, 1.6MB). 4-edge unroll.
__global__ __launch_bounds__(256) void k_agg(const int* __restrict__ rowB,
                                             const int* __restrict__ rowE,
                                             const unsigned short* __restrict__ adjD,
                                             const float* __restrict__ al,
                                             const float* __restrict__ arw,
                                             const unsigned short* __restrict__ h_bf,
                                             const float* __restrict__ bias,
                                             float* __restrict__ out, int N) {
    const int g = threadIdx.x >> 5;
    const int n = blockIdx.x * 8 + g;
    if (n >= N) return;
    const int l  = threadIdx.x & 31;
    const int c0 = l * 4;            // 4 contiguous channels
    const int hh = l >> 3;           // head of this lane's channels
    const int beg = rowB[n], end = rowE[n];
    const float alv = al[n * NH + hh];

    float a0 = 0.f, a1 = 0.f, a2 = 0.f, a3 = 0.f;

    for (int base = beg; base < end; base += 32) {
        int idx = base + l;
        int av  = (idx < end) ? (int)adjD[idx] : 0;   // coop preload (64B/group)
        int cnt = min(32, end - base);
        int e = 0;
        for (; e + 4 <= cnt; e += 4) {
            int s0 = __shfl(av, e,     32);
            int s1 = __shfl(av, e + 1, 32);
            int s2 = __shfl(av, e + 2, 32);
            int s3 = __shfl(av, e + 3, 32);
            ushort4 u0 = *(const ushort4*)(h_bf + (size_t)s0 * HC + c0);
            ushort4 u1 = *(const ushort4*)(h_bf + (size_t)s1 * HC + c0);
            ushort4 u2 = *(const ushort4*)(h_bf + (size_t)s2 * HC + c0);
            ushort4 u3 = *(const ushort4*)(h_bf + (size_t)s3 * HC + c0);
            float2 p0 = *(const float2*)(arw + (size_t)s0 * 8 + hh * 2);
            float2 p1 = *(const float2*)(arw + (size_t)s1 * 8 + hh * 2);
            float2 p2 = *(const float2*)(arw + (size_t)s2 * 8 + hh * 2);
            float2 p3 = *(const float2*)(arw + (size_t)s3 * 8 + hh * 2);
            float t0 = alv + p0.x; t0 = (t0 > 0.f) ? t0 : NEG_SLOPE * t0;
            float t1 = alv + p1.x; t1 = (t1 > 0.f) ? t1 : NEG_SLOPE * t1;
            float t2 = alv + p2.x; t2 = (t2 > 0.f) ? t2 : NEG_SLOPE * t2;
            float t3 = alv + p3.x; t3 = (t3 > 0.f) ? t3 : NEG_SLOPE * t3;
            float w0 = __expf(t0) * p0.y;
            float w1 = __expf(t1) * p1.y;
            float w2 = __expf(t2) * p2.y;
            float w3 = __expf(t3) * p3.y;
            a0 += bf2f(u0.x) * w0; a1 += bf2f(u0.y) * w0;
            a2 += bf2f(u0.z) * w0; a3 += bf2f(u0.w) * w0;
            a0 += bf2f(u1.x) * w1; a1 += bf2f(u1.y) * w1;
            a2 += bf2f(u1.z) * w1; a3 += bf2f(u1.w) * w1;
            a0 += bf2f(u2.x) * w2; a1 += bf2f(u2.y) * w2;
            a2 += bf2f(u2.z) * w2; a3 += bf2f(u2.w) * w2;
            a0 += bf2f(u3.x) * w3; a1 += bf2f(u3.y) * w3;
            a2 += bf2f(u3.z) * w3; a3 += bf2f(u3.w) * w3;
        }
        for (; e < cnt; e++) {
            int s0 = __shfl(av, e, 32);
            ushort4 u0 = *(const ushort4*)(h_bf + (size_t)s0 * HC + c0);
            float2 p0 = *(const float2*)(arw + (size_t)s0 * 8 + hh * 2);
            float t0 = alv + p0.x; t0 = (t0 > 0.f) ? t0 : NEG_SLOPE * t0;
            float w0 = __expf(t0) * p0.y;
            a0 += bf2f(u0.x) * w0; a1 += bf2f(u0.y) * w0;
            a2 += bf2f(u0.z) * w0; a3 += bf2f(u0.w) * w0;
        }
    }
    float4 b4 = *(const float4*)(bias + c0);
    *(float4*)(out + (size_t)n * HC + c0) =
        make_float4(a0 + b4.x, a1 + b4.y, a2 + b4.z, a3 + b4.w);
}

extern "C" void kernel_launch(void* const* d_in, const int* in_sizes, int n_in,
                              void* d_out, int out_size, void* d_ws, size_t ws_size,
                              hipStream_t stream) {
    const float* x    = (const float*)d_in[0];
    const float* W    = (const float*)d_in[1];
    const float* att  = (const float*)d_in[2];
    const float* bias = (const float*)d_in[3];
    const int*   ei   = (const int*)d_in[4];

    const int N  = in_sizes[0] / IND;     // 50000
    const int E  = in_sizes[4] / 2;       // 800000
    const int NE = E + N;
    const int ncb = (N + (1 << CSH) - 1) >> CSH;   // 196
    const int nsb = (NE + CHUNK - 1) / CHUNK;      // 208 scatter blocks
    const int ngb = (N + 255) / 256;               // 196 gemm blocks (512 thr)
    float* out = (float*)d_out;
    const int nodeTot = N * NH;
    const size_t capTot = (size_t)ncb * BCAP;      // 196*6144 ≈ 1.2M recs/side

    // ws layout
    unsigned short* h_bf  = (unsigned short*)d_ws;             // N*128 u16 = 12.8MB
    unsigned short* WT_bf = h_bf + (size_t)N * HC;             // 32K u16
    float* al   = (float*)(WT_bf + IND * HC);                  // N*4 f32
    float* ar   = al + nodeTot;                                // N*4
    float* arw  = ar + nodeTot;                                // N*8 = 1.6MB
    unsigned int* recS = (unsigned int*)(arw + (size_t)N * 8); // ncb*BCAP u32
    unsigned int* recD = recS + capTot;                        // ncb*BCAP u32
    unsigned short* adjD = (unsigned short*)(recD + capTot);   // ncb*BCAP u16
    int* rowB    = (int*)(adjD + capTot + (capTot & 1));       // N
    int* rowE    = rowB + N;                                   // N
    int* gcurS   = rowE + N;                                   // ncb
    int* gcurD   = gcurS + NCB_MAX;                            // ncb

    k_wprep<<<(IND * HC + 255) / 256, 256, 0, stream>>>(W, WT_bf, gcurS, gcurD);
    k_gs<<<nsb + ngb, 512, 0, stream>>>(x, WT_bf, att, h_bf, al, ar, ei,
                                        gcurS, gcurD, recS, recD,
                                        E, NE, ncb, nsb, N);
    k_bucket<<<2 * ncb, 256, 0, stream>>>(recS, recD, gcurS, gcurD, al, ar,
                                          adjD, rowB, rowE, arw, ncb, N);
    k_agg<<<(N + 7) / 8, 256, 0, stream>>>(rowB, rowE, adjD, al, arw, h_bf,
                                           bias, out, N);
}